// Round 2
// baseline (986.536 us; speedup 1.0000x reference)
//
#include <hip/hip_runtime.h>

#define N_ROWS 131072
#define KCODES 1024
#define DIM 64
#define BLOCK 256
#define ROWS_PB 128
#define KHALF (KCODES / 2)

// ||c||^2 for all codes, computed once by a tiny pre-kernel with the exact
// pairwise bit-formula the passing kernel used. Read back via uniform s_load.
__device__ float g_c2[KCODES];

__global__ void __launch_bounds__(BLOCK)
c2_pre(const float* __restrict__ cb)
{
#pragma clang fp contract(off)
    const int code = blockIdx.x * BLOCK + threadIdx.x;
    const float* c = cb + code * DIM;
    float r0 = c[0]*c[0], r1 = c[1]*c[1], r2 = c[2]*c[2], r3 = c[3]*c[3];
    float r4 = c[4]*c[4], r5 = c[5]*c[5], r6 = c[6]*c[6], r7 = c[7]*c[7];
#pragma unroll
    for (int i = 1; i < 8; ++i) {
        r0 = r0 + c[i*8+0]*c[i*8+0];
        r1 = r1 + c[i*8+1]*c[i*8+1];
        r2 = r2 + c[i*8+2]*c[i*8+2];
        r3 = r3 + c[i*8+3]*c[i*8+3];
        r4 = r4 + c[i*8+4]*c[i*8+4];
        r5 = r5 + c[i*8+5]*c[i*8+5];
        r6 = r6 + c[i*8+6]*c[i*8+6];
        r7 = r7 + c[i*8+7]*c[i*8+7];
    }
    g_c2[code] = ((r0 + r1) + (r2 + r3)) + ((r4 + r5) + (r6 + r7));
}

// h: [32, 64, 64, 64] fp32 (B, D, H, W); codebook: [1024, 64] fp32
// out: z[131072] as float ++ q[131072*64] fp32
//
// Row-per-lane structure: each lane owns one x-row in 64 VGPRs for the whole
// kernel. Codes are wave-uniform -> s_load into SGPRs (64 B/instr SMEM return
// for the whole wave, vs 4 KB/instr replicated LDS return). Inner loop:
// 64 v_fma (v,v,s) + ~5 SMEM + 6 VALU epilogue per code. Zero LDS, zero VMEM.
// Each row's k-range is split across 2 waves (waves 0,1 = k<512; waves 2,3 =
// k>=512) -> 4096 waves total = 4 waves/SIMD resident to hide the serial
// fma chain + SMEM latency. Merge keeps global k order => np first-index ties.
__global__ void
__attribute__((amdgpu_flat_work_group_size(256, 256), amdgpu_waves_per_eu(4)))
vq_main(const float* __restrict__ h,
        const float* __restrict__ cb,
        float* __restrict__ z_out,
        float* __restrict__ q_out)
{
    __shared__ float mbd[ROWS_PB];    // khalf0 best dist
    __shared__ int   mbk[ROWS_PB];    // khalf0 best idx
    __shared__ int   s_idx[ROWS_PB];  // final idx for q gather

    const int tid   = threadIdx.x;
    const int lane  = tid & 63;
    const int wave  = tid >> 6;            // 0..3
    const int khalf = wave >> 1;           // 0: k in [0,512), 1: [512,1024)
    const int rloc  = (wave & 1) * 64 + lane;   // 0..127
    const int row0  = blockIdx.x * ROWS_PB;
    const int row   = row0 + rloc;
    const int bb    = row >> 12;           // whole block shares bb (128 | 4096)
    const int yx    = row & 4095;

    // ---- x row into registers (coalesced across lanes for each d) ----
    float xr[DIM];
    {
        const float* hb = h + (size_t)bb * (DIM * 4096) + yx;
#pragma unroll
        for (int d = 0; d < DIM; ++d)
            xr[d] = hb[(size_t)d * 4096];
    }

    // ---- Sv = ||x||^2, exact pairwise bit-formula as before ----
    float Sv;
    {
#pragma clang fp contract(off)
        float r0 = xr[0]*xr[0], r1 = xr[1]*xr[1], r2 = xr[2]*xr[2], r3 = xr[3]*xr[3];
        float r4 = xr[4]*xr[4], r5 = xr[5]*xr[5], r6 = xr[6]*xr[6], r7 = xr[7]*xr[7];
#pragma unroll
        for (int i = 1; i < 8; ++i) {
            r0 = r0 + xr[i*8+0]*xr[i*8+0];
            r1 = r1 + xr[i*8+1]*xr[i*8+1];
            r2 = r2 + xr[i*8+2]*xr[i*8+2];
            r3 = r3 + xr[i*8+3]*xr[i*8+3];
            r4 = r4 + xr[i*8+4]*xr[i*8+4];
            r5 = r5 + xr[i*8+5]*xr[i*8+5];
            r6 = r6 + xr[i*8+6]*xr[i*8+6];
            r7 = r7 + xr[i*8+7]*xr[i*8+7];
        }
        Sv = ((r0 + r1) + (r2 + r3)) + ((r4 + r5) + (r6 + r7));
    }

    // ---- argmin over this wave's k-half ----
    float bd = 3.4e38f;
    int   bk = 0;
    const int kbeg = khalf * KHALF;
    const int kend = kbeg + KHALF;

#pragma unroll 1
    for (int k = kbeg; k < kend; ++k) {
        // wave-uniform loads -> SGPRs (s_load_dwordx16 x4 + s_load_dword)
        const float4* cr = (const float4*)(cb + (size_t)k * DIM);
        float4 cv[16];
#pragma unroll
        for (int j = 0; j < 16; ++j) cv[j] = cr[j];
        const float c2v = g_c2[k];

        // sequential fma over d = 0..63 — identical rounding to reference
        float acc = 0.0f;
#pragma unroll
        for (int j = 0; j < 16; ++j) {
            acc = __builtin_fmaf(xr[4*j+0], cv[j].x, acc);
            acc = __builtin_fmaf(xr[4*j+1], cv[j].y, acc);
            acc = __builtin_fmaf(xr[4*j+2], cv[j].z, acc);
            acc = __builtin_fmaf(xr[4*j+3], cv[j].w, acc);
        }

        {
#pragma clang fp contract(off)
            const float t  = 2.0f * acc;   // exact
            const float u  = Sv - t;       // rounded like np
            const float d2 = u + c2v;
            if (d2 < bd) { bd = d2; bk = k; }   // strict < => first index wins
        }
    }

    // ---- merge k-halves: khalf0 wins ties (smaller k) => np first-index ----
    if (khalf == 0) { mbd[rloc] = bd; mbk[rloc] = bk; }
    __syncthreads();
    if (khalf == 1) {
        const float d0  = mbd[rloc];
        const int   kk0 = mbk[rloc];
        const int   fk  = (bd < d0) ? bk : kk0;
        z_out[row]  = (float)fk;
        s_idx[rloc] = fk;
    }
    __syncthreads();

    // ---- q gather: bit-exact codebook rows, coalesced float4 stores ----
    const float4* cb4 = (const float4*)cb;
    float4* q4 = (float4*)q_out;
#pragma unroll
    for (int it = 0; it < 8; ++it) {
        const int slot = it * BLOCK + tid;    // 0..2047
        const int rl   = slot >> 4;           // row 0..127
        const int c4   = slot & 15;
        q4[(size_t)(row0 + rl) * 16 + c4] = cb4[s_idx[rl] * 16 + c4];
    }
}

extern "C" void kernel_launch(void* const* d_in, const int* in_sizes, int n_in,
                              void* d_out, int out_size, void* d_ws, size_t ws_size,
                              hipStream_t stream) {
    const float* h  = (const float*)d_in[0];
    const float* cb = (const float*)d_in[1];
    float* out   = (float*)d_out;
    float* z_out = out;              // 131072 floats
    float* q_out = out + N_ROWS;     // 131072*64 floats
    (void)d_ws; (void)ws_size;

    c2_pre<<<dim3(KCODES / BLOCK), dim3(BLOCK), 0, stream>>>(cb);
    vq_main<<<dim3(N_ROWS / ROWS_PB), dim3(BLOCK), 0, stream>>>(h, cb, z_out, q_out);
}